// Round 7
// baseline (357.627 us; speedup 1.0000x reference)
//
#include <hip/hip_runtime.h>

typedef __attribute__((ext_vector_type(8))) short short8;   // 8 bf16 = 4 VGPRs
typedef __attribute__((ext_vector_type(4))) float floatx4;  // MFMA acc / NT store

#define N_PTS 8192
#define D_DIM 256
#define N_PLANES 128
// zero-fill split: norm fills first 224 MB, keys fills last 32 MB
#define NORM_FILL_FLOATS 58720256  // 8192 blocks x 7168 floats
#define KEYS_FILL_FLOATS 16384     // per keys block (512 blocks x 64 KB)

// round-to-nearest-even float -> bf16 bits
__device__ inline unsigned short f2bf(float f) {
    unsigned int x = __float_as_uint(f);
    unsigned int r = (x + 0x7fffu + ((x >> 16) & 1u)) >> 16;
    return (unsigned short)r;
}

// count of zero bytes in w (exact per-byte SWAR, no cross-byte carry)
__device__ inline int zbytes(unsigned int w) {
    unsigned int t = ((w & 0x7f7f7f7fu) + 0x7f7f7f7fu) | w | 0x7f7f7f7fu;
    return __popc(~t);  // ~t has only bit7 per byte set, iff byte == 0
}

// async global->LDS, 16B per lane; LDS dest must be base + lane*16 (m104/m108)
__device__ inline void load_lds16(const unsigned short* g, unsigned short* l) {
    __builtin_amdgcn_global_load_lds(
        (const __attribute__((address_space(1))) unsigned int*)g,
        (__attribute__((address_space(3))) unsigned int*)l, 16, 0, 0);
}

// ---------------------------------------------------------------------------
// Kernel 1: row-normalize Z (fp32) -> Zn (bf16), one wave per row, PLUS
// zero-fill of out[0 .. 224MB): 28 NT floatx4 stores/thread, no barrier
// anywhere -> stores stream at full write BW while norm compute hides under.
// ---------------------------------------------------------------------------
__global__ void norm_kernel(const float* __restrict__ Z,
                            unsigned short* __restrict__ Zn,
                            float* __restrict__ out) {
    int n = blockIdx.x;
    int lane = threadIdx.x;  // 0..63
    const float4* zr = (const float4*)(Z + (size_t)n * D_DIM);
    float4 v = zr[lane];  // 64 lanes x 4 floats = 256
    float ss = v.x * v.x + v.y * v.y + v.z * v.z + v.w * v.w;
#pragma unroll
    for (int off = 32; off > 0; off >>= 1) ss += __shfl_down(ss, off);
    ss = __shfl(ss, 0);
    float inv = rsqrtf(ss);
    ushort4 o;
    o.x = f2bf(v.x * inv);
    o.y = f2bf(v.y * inv);
    o.z = f2bf(v.z * inv);
    o.w = f2bf(v.w * inv);
    ((ushort4*)(Zn + (size_t)n * D_DIM))[lane] = o;

    // zero-fill share: 7168 floats (28 KB) at block offset, 1 KB/wave-instr
    floatx4 z4 = {0.f, 0.f, 0.f, 0.f};
    float* fb = out + (size_t)n * 7168 + lane * 4;
#pragma unroll
    for (int i = 0; i < 28; ++i)
        __builtin_nontemporal_store(z4, (floatx4*)(fb + i * 256));
}

// ---------------------------------------------------------------------------
// Kernel 2: LSH keys (512 blocks x 16 points) PLUS zero-fill of the last
// 32 MB of out, issued AFTER the one barrier so no vmcnt drain ever waits
// on the stores -- they overlap the dot-product compute.
// keys4[n][w]: word w = ballot bits of planes 32w..32w+31; byte b of the
// 16-byte key equals the reference band-b signature (same 2^r weighting).
// ---------------------------------------------------------------------------
__global__ __launch_bounds__(256) void keys_kernel(
    const float* __restrict__ Z, const float* __restrict__ planes,
    unsigned int* __restrict__ keys4, float* __restrict__ out) {
    __shared__ __align__(16) float zs[16][D_DIM];  // 16 KB
    int t = threadIdx.x;
    int base = blockIdx.x * 16;

    const float4* zsrc = (const float4*)(Z + (size_t)base * D_DIM);
    float4* zdst = (float4*)&zs[0][0];
#pragma unroll
    for (int i = 0; i < 4; ++i) zdst[t + i * 256] = zsrc[t + i * 256];
    __syncthreads();

    // zero-fill share (post-barrier: never drained by a barrier)
    {
        floatx4 z4 = {0.f, 0.f, 0.f, 0.f};
        float* fb = out + NORM_FILL_FLOATS +
                    (size_t)blockIdx.x * KEYS_FILL_FLOATS + t * 4;
#pragma unroll
        for (int i = 0; i < 16; ++i)
            __builtin_nontemporal_store(z4, (floatx4*)(fb + i * 1024));
    }

    int p = t & 127;   // plane index
    int hf = t >> 7;   // 0/1 -> points 0..7 / 8..15
    int wave = t >> 6, lane = t & 63;
    const float4* pr = (const float4*)(planes + (size_t)p * D_DIM);

    float acc[8] = {};
    for (int kk = 0; kk < D_DIM / 4; ++kk) {
        float4 pv = pr[kk];
#pragma unroll
        for (int j = 0; j < 8; ++j) {
            float4 zv = *(const float4*)&zs[hf * 8 + j][kk * 4];
            acc[j] += pv.x * zv.x + pv.y * zv.y + pv.z * zv.z + pv.w * zv.w;
        }
    }

#pragma unroll
    for (int j = 0; j < 8; ++j) {
        unsigned long long mask = __ballot(acc[j] >= 0.0f);
        if (lane < 2) {
            keys4[(size_t)(base + hf * 8 + j) * 4 + (wave & 1) * 2 + lane] =
                (unsigned int)(mask >> (32 * lane));
        }
    }
}

// ---------------------------------------------------------------------------
// Kernel 3: sim GEMM (bf16 MFMA) + sparse LSH epilogue. Full 64x64 grid.
// Out is pre-zeroed by kernels 1-2; this kernel stores ONLY survivors
// (threshold+off-diag, exec-masked, rare by LSH construction) -> no dense
// store phase, no store drain at barriers. K staged in 4 chunks of BK=64
// via global_load_lds (16B), chunk-major LDS.
// ---------------------------------------------------------------------------
__global__ __launch_bounds__(256, 3) void gemm_kernel(
    const unsigned short* __restrict__ Zn, const uint4* __restrict__ keys,
    float* __restrict__ out) {
    __shared__ __align__(16) unsigned short stage[2048 * 8];  // 32 KB: As|Bs
    __shared__ uint4 krow[128];
    __shared__ uint4 kcol[128];
    unsigned short* As = stage;         // 8 chunks x 128 rows x 16B
    unsigned short* Bs = stage + 8192;  // same, for B tile

    int t = threadIdx.x;
    int rowBase = blockIdx.y * 128;
    int colBase = blockIdx.x * 128;
    if (t < 128)
        krow[t] = keys[rowBase + t];
    else
        kcol[t - 128] = keys[colBase + (t - 128)];

    int wave = t >> 6, lane = t & 63;
    int wm = wave >> 1, wn = wave & 1;
    int quad = lane >> 4, l16 = lane & 15;

    floatx4 acc[4][4] = {};

    for (int s = 0; s < 4; ++s) {
        __syncthreads();  // fences keys (s=0) / prev-stage LDS reads
#pragma unroll
        for (int i = 0; i < 4; ++i) {
            int sa = i * 256 + t;             // slot 0..1023
            int c = sa >> 7, row = sa & 127;  // chunk, tile-row
            size_t gOff = (size_t)row * D_DIM + s * 64 + c * 8;
            load_lds16(Zn + (size_t)rowBase * D_DIM + gOff, &As[sa * 8]);
            load_lds16(Zn + (size_t)colBase * D_DIM + gOff, &Bs[sa * 8]);
        }
        __syncthreads();  // staging complete

#pragma unroll
        for (int k2 = 0; k2 < 2; ++k2) {
            int cb = k2 * 4 + quad;
            short8 afr[4], bfr[4];
#pragma unroll
            for (int mt = 0; mt < 4; ++mt)
                afr[mt] = *(const short8*)&As[(cb * 128 + wm * 64 + mt * 16 + l16) * 8];
#pragma unroll
            for (int nt = 0; nt < 4; ++nt)
                bfr[nt] = *(const short8*)&Bs[(cb * 128 + wn * 64 + nt * 16 + l16) * 8];
#pragma unroll
            for (int mt = 0; mt < 4; ++mt)
#pragma unroll
                for (int nt = 0; nt < 4; ++nt)
                    acc[mt][nt] = __builtin_amdgcn_mfma_f32_16x16x32_bf16(
                        afr[mt], bfr[nt], acc[mt][nt], 0, 0, 0);
        }
    }

    // Sparse epilogue. C/D layout: col = lane&15, row = quad*4 + reg
    // [m89/m91 verified]. Store only survivors (threshold+off-diag).
#pragma unroll
    for (int mt = 0; mt < 4; ++mt) {
#pragma unroll
        for (int nt = 0; nt < 4; ++nt) {
            int lj = nt * 16 + l16;  // col within wave quadrant, 0..63
            int gj = colBase + wn * 64 + lj;
            uint4 kj = kcol[wn * 64 + lj];
#pragma unroll
            for (int r = 0; r < 4; ++r) {
                int liL = wm * 64 + mt * 16 + quad * 4 + r;
                int gi = rowBase + liL;
                float s = acc[mt][nt][r];
                if (s >= 0.5f && gi != gj) {
                    uint4 ki = krow[liL];
                    int c = zbytes(ki.x ^ kj.x) + zbytes(ki.y ^ kj.y) +
                            zbytes(ki.z ^ kj.z) + zbytes(ki.w ^ kj.w);
                    out[(size_t)gi * N_PTS + gj] = s * (float)c;
                }
            }
        }
    }
}

extern "C" void kernel_launch(void* const* d_in, const int* in_sizes, int n_in,
                              void* d_out, int out_size, void* d_ws,
                              size_t ws_size, hipStream_t stream) {
    const float* Z = (const float*)d_in[0];       // (8192, 256) fp32
    const float* planes = (const float*)d_in[1];  // (128, 256) fp32
    float* out = (float*)d_out;                   // (8192, 8192) fp32

    unsigned short* Zn = (unsigned short*)d_ws;  // 8192*256 bf16 = 4 MB
    unsigned int* keys4 =
        (unsigned int*)((char*)d_ws + (size_t)N_PTS * D_DIM * 2);  // 128 KB

    norm_kernel<<<N_PTS, 64, 0, stream>>>(Z, Zn, out);
    keys_kernel<<<N_PTS / 16, 256, 0, stream>>>(Z, planes, keys4, out);
    gemm_kernel<<<dim3(N_PTS / 128, N_PTS / 128), 256, 0, stream>>>(
        Zn, (const uint4*)keys4, out);
}

// Round 8
// 324.352 us; speedup vs baseline: 1.1026x; 1.1026x over previous
//
#include <hip/hip_runtime.h>

typedef __attribute__((ext_vector_type(8))) short short8;   // 8 bf16 = 4 VGPRs
typedef __attribute__((ext_vector_type(4))) float floatx4;  // MFMA acc / NT store

#define N_PTS 8192
#define D_DIM 256
#define N_PLANES 128
#define NTILE 64  // 8192 / 128

// round-to-nearest-even float -> bf16 bits
__device__ inline unsigned short f2bf(float f) {
    unsigned int x = __float_as_uint(f);
    unsigned int r = (x + 0x7fffu + ((x >> 16) & 1u)) >> 16;
    return (unsigned short)r;
}

// count of zero bytes in w (exact per-byte SWAR, no cross-byte carry)
__device__ inline int zbytes(unsigned int w) {
    unsigned int t = ((w & 0x7f7f7f7fu) + 0x7f7f7f7fu) | w | 0x7f7f7f7fu;
    return __popc(~t);  // ~t has only bit7 per byte set, iff byte == 0
}

// async global->LDS, 16B per lane; LDS dest must be base + lane*16 (m104/m108)
__device__ inline void load_lds16(const unsigned short* g, unsigned short* l) {
    __builtin_amdgcn_global_load_lds(
        (const __attribute__((address_space(1))) unsigned int*)g,
        (__attribute__((address_space(3))) unsigned int*)l, 16, 0, 0);
}

// ---------------------------------------------------------------------------
// Kernel 1: row-normalize Z (fp32) -> Zn (bf16). One wave per row.
// ---------------------------------------------------------------------------
__global__ void norm_kernel(const float* __restrict__ Z,
                            unsigned short* __restrict__ Zn) {
    int n = blockIdx.x;
    int lane = threadIdx.x;  // 0..63
    const float4* zr = (const float4*)(Z + (size_t)n * D_DIM);
    float4 v = zr[lane];  // 64 lanes x 4 floats = 256
    float ss = v.x * v.x + v.y * v.y + v.z * v.z + v.w * v.w;
#pragma unroll
    for (int off = 32; off > 0; off >>= 1) ss += __shfl_down(ss, off);
    ss = __shfl(ss, 0);
    float inv = rsqrtf(ss);
    ushort4 o;
    o.x = f2bf(v.x * inv);
    o.y = f2bf(v.y * inv);
    o.z = f2bf(v.z * inv);
    o.w = f2bf(v.w * inv);
    ((ushort4*)(Zn + (size_t)n * D_DIM))[lane] = o;
}

// ---------------------------------------------------------------------------
// Kernel 2: LSH keys (512 blocks x 16 points, 2 blocks/CU).
// keys4[n][w]: word w = ballot bits of planes 32w..32w+31; byte b of the
// 16-byte key equals the reference band-b signature (same 2^r weighting).
// ---------------------------------------------------------------------------
__global__ __launch_bounds__(256) void keys_kernel(
    const float* __restrict__ Z, const float* __restrict__ planes,
    unsigned int* __restrict__ keys4) {
    __shared__ __align__(16) float zs[16][D_DIM];  // 16 KB
    int t = threadIdx.x;
    int base = blockIdx.x * 16;

    const float4* zsrc = (const float4*)(Z + (size_t)base * D_DIM);
    float4* zdst = (float4*)&zs[0][0];
#pragma unroll
    for (int i = 0; i < 4; ++i) zdst[t + i * 256] = zsrc[t + i * 256];
    __syncthreads();

    int p = t & 127;   // plane index
    int hf = t >> 7;   // 0/1 -> points 0..7 / 8..15
    int wave = t >> 6, lane = t & 63;
    const float4* pr = (const float4*)(planes + (size_t)p * D_DIM);

    float acc[8] = {};
    for (int kk = 0; kk < D_DIM / 4; ++kk) {
        float4 pv = pr[kk];
#pragma unroll
        for (int j = 0; j < 8; ++j) {
            float4 zv = *(const float4*)&zs[hf * 8 + j][kk * 4];
            acc[j] += pv.x * zv.x + pv.y * zv.y + pv.z * zv.z + pv.w * zv.w;
        }
    }

#pragma unroll
    for (int j = 0; j < 8; ++j) {
        unsigned long long mask = __ballot(acc[j] >= 0.0f);
        if (lane < 2) {
            keys4[(size_t)(base + hf * 8 + j) * 4 + (wave & 1) * 2 + lane] =
                (unsigned int)(mask >> (32 * lane));
        }
    }
}

// ---------------------------------------------------------------------------
// Kernel 3: sim GEMM (bf16 MFMA) + LSH epilogue, TRIANGULAR grid (2080
// blocks, bi<=bj): halves MFMA/LDS/staging vs full grid. Mirror tile gets
// prologue NT zero-stores (zeros are symmetric -> no transpose) + rare
// survivor scatters in the epilogue (ordered: prologue stores drain at the
// first barrier). K-loop double-buffered: stage s+1's global_load_lds
// issued right after barrier s, flying during stage-s compute.
// Own tile stored densely in the epilogue (no barrier after -> free-flow).
// ---------------------------------------------------------------------------
__global__ __launch_bounds__(256) void gemm_kernel(
    const unsigned short* __restrict__ Zn, const uint4* __restrict__ keys,
    float* __restrict__ out) {
    __shared__ __align__(16) unsigned short As[2][8192];  // 2 x 16 KB
    __shared__ __align__(16) unsigned short Bs[2][8192];  // 2 x 16 KB
    __shared__ uint4 krow[128];
    __shared__ uint4 kcol[128];

    // triangular decode: bi = largest b with S(b)=b*64-b*(b-1)/2 <= idx
    int idx = blockIdx.x;
    int bi = (int)((129.0f - sqrtf(16641.0f - 8.0f * (float)idx)) * 0.5f);
    while ((bi + 1) * NTILE - ((bi + 1) * bi) / 2 <= idx) ++bi;
    while (bi * NTILE - (bi * (bi - 1)) / 2 > idx) --bi;
    int bj = bi + (idx - (bi * NTILE - (bi * (bi - 1)) / 2));
    int rowBase = bi * 128;
    int colBase = bj * 128;
    bool diag = (bi == bj);

    int t = threadIdx.x;
    if (t < 128)
        krow[t] = keys[rowBase + t];
    else
        kcol[t - 128] = keys[colBase + (t - 128)];

    // issue stage-0 loads first (head of memory queue)
    const unsigned short* ZnA = Zn + (size_t)rowBase * D_DIM;
    const unsigned short* ZnB = Zn + (size_t)colBase * D_DIM;
#pragma unroll
    for (int i = 0; i < 4; ++i) {
        int sa = i * 256 + t;             // slot 0..1023
        int c = sa >> 7, row = sa & 127;  // 16B-chunk, tile-row
        size_t gOff = (size_t)row * D_DIM + c * 8;
        load_lds16(ZnA + gOff, &As[0][sa * 8]);
        load_lds16(ZnB + gOff, &Bs[0][sa * 8]);
    }

    // mirror-tile zero fill (tile (bj,bi)), NT; drains at first barrier
    if (!diag) {
        float* mOut = out + (size_t)colBase * N_PTS + rowBase;
        floatx4 z4 = {0.f, 0.f, 0.f, 0.f};
#pragma unroll
        for (int i = 0; i < 16; ++i) {
            int slot = i * 256 + t;  // 0..4095
            int row = slot >> 5;     // 0..127
            int c4 = slot & 31;      // float4 column
            __builtin_nontemporal_store(
                z4, (floatx4*)(mOut + (size_t)row * N_PTS + c4 * 4));
        }
    }

    int wave = t >> 6, lane = t & 63;
    int wm = wave >> 1, wn = wave & 1;
    int quad = lane >> 4, l16 = lane & 15;

    floatx4 acc[4][4] = {};

    for (int s = 0; s < 4; ++s) {
        int b = s & 1;
        __syncthreads();  // drains stage-s loads (+ mirror stores at s=0)
        if (s < 3) {      // prefetch next stage into other buffer
            int nb = b ^ 1;
#pragma unroll
            for (int i = 0; i < 4; ++i) {
                int sa = i * 256 + t;
                int c = sa >> 7, row = sa & 127;
                size_t gOff = (size_t)row * D_DIM + (s + 1) * 64 + c * 8;
                load_lds16(ZnA + gOff, &As[nb][sa * 8]);
                load_lds16(ZnB + gOff, &Bs[nb][sa * 8]);
            }
        }
#pragma unroll
        for (int k2 = 0; k2 < 2; ++k2) {
            int cb = k2 * 4 + quad;
            short8 afr[4], bfr[4];
#pragma unroll
            for (int mt = 0; mt < 4; ++mt)
                afr[mt] = *(const short8*)&As[b][(cb * 128 + wm * 64 + mt * 16 + l16) * 8];
#pragma unroll
            for (int nt = 0; nt < 4; ++nt)
                bfr[nt] = *(const short8*)&Bs[b][(cb * 128 + wn * 64 + nt * 16 + l16) * 8];
#pragma unroll
            for (int mt = 0; mt < 4; ++mt)
#pragma unroll
                for (int nt = 0; nt < 4; ++nt)
                    acc[mt][nt] = __builtin_amdgcn_mfma_f32_16x16x32_bf16(
                        afr[mt], bfr[nt], acc[mt][nt], 0, 0, 0);
        }
    }

    // Epilogue (no barriers after: stores free-flow). C/D layout:
    // col = lane&15, row = quad*4 + reg [m89/m91 verified].
    // Dense own-tile store; rare survivors also scatter to mirror tile.
#pragma unroll
    for (int mt = 0; mt < 4; ++mt) {
#pragma unroll
        for (int nt = 0; nt < 4; ++nt) {
            int lj = nt * 16 + l16;  // col within wave quadrant, 0..63
            int gj = colBase + wn * 64 + lj;
            uint4 kj = kcol[wn * 64 + lj];
#pragma unroll
            for (int r = 0; r < 4; ++r) {
                int liL = wm * 64 + mt * 16 + quad * 4 + r;
                int gi = rowBase + liL;
                float s = acc[mt][nt][r];
                float v = 0.0f;
                if (s >= 0.5f && gi != gj) {
                    uint4 ki = krow[liL];
                    int c = zbytes(ki.x ^ kj.x) + zbytes(ki.y ^ kj.y) +
                            zbytes(ki.z ^ kj.z) + zbytes(ki.w ^ kj.w);
                    v = s * (float)c;
                }
                __builtin_nontemporal_store(v, out + (size_t)gi * N_PTS + gj);
                if (v != 0.0f && !diag)  // mirror survivor (rare)
                    out[(size_t)gj * N_PTS + gi] = v;
            }
        }
    }
}

extern "C" void kernel_launch(void* const* d_in, const int* in_sizes, int n_in,
                              void* d_out, int out_size, void* d_ws,
                              size_t ws_size, hipStream_t stream) {
    const float* Z = (const float*)d_in[0];       // (8192, 256) fp32
    const float* planes = (const float*)d_in[1];  // (128, 256) fp32
    float* out = (float*)d_out;                   // (8192, 8192) fp32

    unsigned short* Zn = (unsigned short*)d_ws;  // 8192*256 bf16 = 4 MB
    unsigned int* keys4 =
        (unsigned int*)((char*)d_ws + (size_t)N_PTS * D_DIM * 2);  // 128 KB

    norm_kernel<<<N_PTS, 64, 0, stream>>>(Z, Zn);
    keys_kernel<<<N_PTS / 16, 256, 0, stream>>>(Z, planes, keys4);
    int nblocks = NTILE * (NTILE + 1) / 2;  // 2080 upper-tri 128x128 tiles
    gemm_kernel<<<nblocks, 256, 0, stream>>>(Zn, (const uint4*)keys4, out);
}

// Round 9
// 314.344 us; speedup vs baseline: 1.1377x; 1.0318x over previous
//
#include <hip/hip_runtime.h>

typedef __attribute__((ext_vector_type(8))) short short8;   // 8 bf16 = 4 VGPRs
typedef __attribute__((ext_vector_type(4))) float floatx4;  // MFMA acc / NT store

#define N_PTS 8192
#define D_DIM 256
#define N_PLANES 128
#define NTILE 64  // 8192 / 128

// round-to-nearest-even float -> bf16 bits
__device__ inline unsigned short f2bf(float f) {
    unsigned int x = __float_as_uint(f);
    unsigned int r = (x + 0x7fffu + ((x >> 16) & 1u)) >> 16;
    return (unsigned short)r;
}

// count of zero bytes in w (exact per-byte SWAR, no cross-byte carry)
__device__ inline int zbytes(unsigned int w) {
    unsigned int t = ((w & 0x7f7f7f7fu) + 0x7f7f7f7fu) | w | 0x7f7f7f7fu;
    return __popc(~t);  // ~t has only bit7 per byte set, iff byte == 0
}

// async global->LDS, 16B per lane; LDS dest must be base + lane*16 (m104/m108)
__device__ inline void load_lds16(const unsigned short* g, unsigned short* l) {
    __builtin_amdgcn_global_load_lds(
        (const __attribute__((address_space(1))) unsigned int*)g,
        (__attribute__((address_space(3))) unsigned int*)l, 16, 0, 0);
}

// ---------------------------------------------------------------------------
// Kernel 1: row-normalize Z (fp32) -> Zn (bf16). One wave per row.
// ---------------------------------------------------------------------------
__global__ void norm_kernel(const float* __restrict__ Z,
                            unsigned short* __restrict__ Zn) {
    int n = blockIdx.x;
    int lane = threadIdx.x;  // 0..63
    const float4* zr = (const float4*)(Z + (size_t)n * D_DIM);
    float4 v = zr[lane];  // 64 lanes x 4 floats = 256
    float ss = v.x * v.x + v.y * v.y + v.z * v.z + v.w * v.w;
#pragma unroll
    for (int off = 32; off > 0; off >>= 1) ss += __shfl_down(ss, off);
    ss = __shfl(ss, 0);
    float inv = rsqrtf(ss);
    ushort4 o;
    o.x = f2bf(v.x * inv);
    o.y = f2bf(v.y * inv);
    o.z = f2bf(v.z * inv);
    o.w = f2bf(v.w * inv);
    ((ushort4*)(Zn + (size_t)n * D_DIM))[lane] = o;
}

// ---------------------------------------------------------------------------
// Kernel 2: LSH keys (512 blocks x 16 points).
// keys4[n][w]: word w = ballot bits of planes 32w..32w+31; byte b of the
// 16-byte key equals the reference band-b signature (same 2^r weighting).
// ---------------------------------------------------------------------------
__global__ __launch_bounds__(256) void keys_kernel(
    const float* __restrict__ Z, const float* __restrict__ planes,
    unsigned int* __restrict__ keys4) {
    __shared__ __align__(16) float zs[16][D_DIM];  // 16 KB
    int t = threadIdx.x;
    int base = blockIdx.x * 16;

    const float4* zsrc = (const float4*)(Z + (size_t)base * D_DIM);
    float4* zdst = (float4*)&zs[0][0];
#pragma unroll
    for (int i = 0; i < 4; ++i) zdst[t + i * 256] = zsrc[t + i * 256];
    __syncthreads();

    int p = t & 127;   // plane index
    int hf = t >> 7;   // 0/1 -> points 0..7 / 8..15
    int wave = t >> 6, lane = t & 63;
    const float4* pr = (const float4*)(planes + (size_t)p * D_DIM);

    float acc[8] = {};
    for (int kk = 0; kk < D_DIM / 4; ++kk) {
        float4 pv = pr[kk];
#pragma unroll
        for (int j = 0; j < 8; ++j) {
            float4 zv = *(const float4*)&zs[hf * 8 + j][kk * 4];
            acc[j] += pv.x * zv.x + pv.y * zv.y + pv.z * zv.z + pv.w * zv.w;
        }
    }

#pragma unroll
    for (int j = 0; j < 8; ++j) {
        unsigned long long mask = __ballot(acc[j] >= 0.0f);
        if (lane < 2) {
            keys4[(size_t)(base + hf * 8 + j) * 4 + (wave & 1) * 2 + lane] =
                (unsigned int)(mask >> (32 * lane));
        }
    }
}

// ---------------------------------------------------------------------------
// Kernel 3: sim GEMM (bf16 MFMA) + LSH epilogue, TRIANGULAR grid (2080
// blocks, bi<=bj). R8 evidence: gemm is LATENCY-bound (time ~ work/occupancy)
// -> this round maximizes occupancy: single-buffered staging (36 KB LDS ->
// 4 blocks/CU) + __launch_bounds__(256,4) (VGPR cap 128 -> 16 waves/CU,
// 2x R8). Mirror tile: prologue NT zero-stores (drain at first barrier) +
// rare survivor scatter in epilogue. Own tile: dense NT store, free-flowing
// (no barrier after).
// ---------------------------------------------------------------------------
__global__ __launch_bounds__(256, 4) void gemm_kernel(
    const unsigned short* __restrict__ Zn, const uint4* __restrict__ keys,
    float* __restrict__ out) {
    __shared__ __align__(16) unsigned short As[8192];  // 16 KB: 8 chunks x 128 rows x 16B
    __shared__ __align__(16) unsigned short Bs[8192];  // 16 KB
    __shared__ uint4 krow[128];
    __shared__ uint4 kcol[128];

    // triangular decode: bi = largest b with S(b)=b*64-b*(b-1)/2 <= idx
    int idx = blockIdx.x;
    int bi = (int)((129.0f - sqrtf(16641.0f - 8.0f * (float)idx)) * 0.5f);
    while ((bi + 1) * NTILE - ((bi + 1) * bi) / 2 <= idx) ++bi;
    while (bi * NTILE - (bi * (bi - 1)) / 2 > idx) --bi;
    int bj = bi + (idx - (bi * NTILE - (bi * (bi - 1)) / 2));
    int rowBase = bi * 128;
    int colBase = bj * 128;
    bool diag = (bi == bj);

    int t = threadIdx.x;
    if (t < 128)
        krow[t] = keys[rowBase + t];
    else
        kcol[t - 128] = keys[colBase + (t - 128)];

    const unsigned short* ZnA = Zn + (size_t)rowBase * D_DIM;
    const unsigned short* ZnB = Zn + (size_t)colBase * D_DIM;

    // mirror-tile zero fill (tile (bj,bi)), NT; drains at first barrier
    if (!diag) {
        float* mOut = out + (size_t)colBase * N_PTS + rowBase;
        floatx4 z4 = {0.f, 0.f, 0.f, 0.f};
#pragma unroll
        for (int i = 0; i < 16; ++i) {
            int slot = i * 256 + t;  // 0..4095
            int row = slot >> 5;     // 0..127
            int c4 = slot & 31;      // float4 column
            __builtin_nontemporal_store(
                z4, (floatx4*)(mOut + (size_t)row * N_PTS + c4 * 4));
        }
    }

    int wave = t >> 6, lane = t & 63;
    int wm = wave >> 1, wn = wave & 1;
    int quad = lane >> 4, l16 = lane & 15;

    floatx4 acc[4][4] = {};

    for (int s = 0; s < 4; ++s) {
        __syncthreads();  // prev-stage LDS reads done (s=0: fences keys)
#pragma unroll
        for (int i = 0; i < 4; ++i) {
            int sa = i * 256 + t;             // slot 0..1023
            int c = sa >> 7, row = sa & 127;  // 16B-chunk, tile-row
            size_t gOff = (size_t)row * D_DIM + s * 64 + c * 8;
            load_lds16(ZnA + gOff, &As[sa * 8]);
            load_lds16(ZnB + gOff, &Bs[sa * 8]);
        }
        __syncthreads();  // staging complete (vmcnt drained before barrier)

#pragma unroll
        for (int k2 = 0; k2 < 2; ++k2) {
            int cb = k2 * 4 + quad;
            short8 afr[4], bfr[4];
#pragma unroll
            for (int mt = 0; mt < 4; ++mt)
                afr[mt] = *(const short8*)&As[(cb * 128 + wm * 64 + mt * 16 + l16) * 8];
#pragma unroll
            for (int nt = 0; nt < 4; ++nt)
                bfr[nt] = *(const short8*)&Bs[(cb * 128 + wn * 64 + nt * 16 + l16) * 8];
#pragma unroll
            for (int mt = 0; mt < 4; ++mt)
#pragma unroll
                for (int nt = 0; nt < 4; ++nt)
                    acc[mt][nt] = __builtin_amdgcn_mfma_f32_16x16x32_bf16(
                        afr[mt], bfr[nt], acc[mt][nt], 0, 0, 0);
        }
    }

    // Epilogue (no barriers after: stores free-flow). C/D layout:
    // col = lane&15, row = quad*4 + reg [m89/m91 verified].
    // Dense own-tile store; rare survivors also scatter to mirror tile.
#pragma unroll
    for (int mt = 0; mt < 4; ++mt) {
#pragma unroll
        for (int nt = 0; nt < 4; ++nt) {
            int lj = nt * 16 + l16;  // col within wave quadrant, 0..63
            int gj = colBase + wn * 64 + lj;
            uint4 kj = kcol[wn * 64 + lj];
#pragma unroll
            for (int r = 0; r < 4; ++r) {
                int liL = wm * 64 + mt * 16 + quad * 4 + r;
                int gi = rowBase + liL;
                float s = acc[mt][nt][r];
                float v = 0.0f;
                if (s >= 0.5f && gi != gj) {
                    uint4 ki = krow[liL];
                    int c = zbytes(ki.x ^ kj.x) + zbytes(ki.y ^ kj.y) +
                            zbytes(ki.z ^ kj.z) + zbytes(ki.w ^ kj.w);
                    v = s * (float)c;
                }
                __builtin_nontemporal_store(v, out + (size_t)gi * N_PTS + gj);
                if (v != 0.0f && !diag)  // mirror survivor (rare)
                    out[(size_t)gj * N_PTS + gi] = v;
            }
        }
    }
}

extern "C" void kernel_launch(void* const* d_in, const int* in_sizes, int n_in,
                              void* d_out, int out_size, void* d_ws,
                              size_t ws_size, hipStream_t stream) {
    const float* Z = (const float*)d_in[0];       // (8192, 256) fp32
    const float* planes = (const float*)d_in[1];  // (128, 256) fp32
    float* out = (float*)d_out;                   // (8192, 8192) fp32

    unsigned short* Zn = (unsigned short*)d_ws;  // 8192*256 bf16 = 4 MB
    unsigned int* keys4 =
        (unsigned int*)((char*)d_ws + (size_t)N_PTS * D_DIM * 2);  // 128 KB

    norm_kernel<<<N_PTS, 64, 0, stream>>>(Z, Zn);
    keys_kernel<<<N_PTS / 16, 256, 0, stream>>>(Z, planes, keys4);
    int nblocks = NTILE * (NTILE + 1) / 2;  // 2080 upper-tri 128x128 tiles
    gemm_kernel<<<nblocks, 256, 0, stream>>>(Zn, (const uint4*)keys4, out);
}